// Round 6
// baseline (12070.827 us; speedup 1.0000x reference)
//
#include <hip/hip_runtime.h>

// LSTM persistent recurrence v6 for MI355X.
// 32 WGs = 4 row-groups x 8 hcol-blocks(32). Device-scope tag-in-data protocol
// (proven v5): publish = ONE dwordx4 {h0,tag,h1,tag} per thread; consumers poll
// the data lines (tag==t => fresh). x-prefetch for t+1 issued at loop bottom so
// poll vmcnt(0) is clean and HBM latency hides under the inter-step wait.

#define T_STEPS 2048
#define BATCH   64
#define DIM     256
#define HID     256
#define PKEEP   0.7f
#define NG      4                        // row groups
#define RPG     16                       // rows per group
#define NCB     8                        // hcol blocks
#define HPB     32                       // hcols per block
#define REGION_U32 (RPG * HID * 2)       // 8192 u32 (pairs) per row-group
#define PLANE_U32  (NG * REGION_U32)     // 32768 u32 (128KB)
#define XEL     (T_STEPS * BATCH * DIM)  // 33554432

typedef __attribute__((ext_vector_type(8))) short s16x8;
typedef __attribute__((ext_vector_type(4))) float f32x4;
typedef __attribute__((ext_vector_type(4))) unsigned int u32x4;
typedef unsigned int u32;
typedef unsigned short u16;

#define HBUF_OFF 4096
#define BIG_OFF  (1 << 20)
#define ZERO_INTS (2 * PLANE_U32)        // both parity planes

#define HISEL 0x07060302u
#define LOSEL 0x05040100u

__device__ __forceinline__ u16 f2bf_rne(float f) {
  unsigned x = __float_as_uint(f);
  return (u16)((x + 0x7fffu + ((x >> 16) & 1u)) >> 16);
}
__device__ __forceinline__ float bf2f(u16 u) { return __uint_as_float(((unsigned)u) << 16); }
__device__ __forceinline__ float sigm(float v) { return 1.0f / (1.0f + __expf(-v)); }
__device__ __forceinline__ float tanh_f(float v) {
  float e = __expf(-2.0f * fabsf(v));
  float r = (1.0f - e) / (1.0f + e);
  return v < 0.0f ? -r : r;
}
__device__ __forceinline__ u32 packbf(float v) {
  u32 uh = __float_as_uint(v) & 0xFFFF0000u;         // hi = trunc
  u32 lo = (u32)f2bf_rne(v - __uint_as_float(uh));   // lo = RNE residual
  return uh | lo;
}
__device__ __forceinline__ void dev_st_u32x4(u32* p, u32x4 v) {
  asm volatile("global_store_dwordx4 %0, %1, off sc0 sc1" :: "v"(p), "v"(v) : "memory");
}
__device__ __forceinline__ void unpack8(u32x4 a, u32x4 b, s16x8& hi, s16x8& lo) {
  u32x4 H, L;
  H[0] = __builtin_amdgcn_perm(a[1], a[0], HISEL);
  H[1] = __builtin_amdgcn_perm(a[3], a[2], HISEL);
  H[2] = __builtin_amdgcn_perm(b[1], b[0], HISEL);
  H[3] = __builtin_amdgcn_perm(b[3], b[2], HISEL);
  L[0] = __builtin_amdgcn_perm(a[1], a[0], LOSEL);
  L[1] = __builtin_amdgcn_perm(a[3], a[2], LOSEL);
  L[2] = __builtin_amdgcn_perm(b[1], b[0], LOSEL);
  L[3] = __builtin_amdgcn_perm(b[3], b[2], LOSEL);
  hi = __builtin_bit_cast(s16x8, H);
  lo = __builtin_bit_cast(s16x8, L);
}

__global__ void lstm_zero_ws(u32* __restrict__ p) {
  int i = blockIdx.x * 256 + threadIdx.x;
  if (i < ZERO_INTS) p[i] = 0;
}

__global__ void lstm_xpack(const float* __restrict__ x, u32* __restrict__ xpk) {
  long i = ((long)blockIdx.x * 256 + threadIdx.x) * 4;
  if (i >= (long)XEL) return;
  f32x4 v = *(const f32x4*)(x + i);
  u32x4 o;
#pragma unroll
  for (int e = 0; e < 4; ++e) o[e] = packbf(v[e] * PKEEP);
  *(u32x4*)(xpk + i) = o;
}

// MODE: 0 = xpack planes, 1 = direct fp32 convert
template <int MODE>
__device__ __forceinline__ void recur_body(
    const float* __restrict__ x, const int* __restrict__ lens,
    const float* __restrict__ W, const float* __restrict__ U,
    const float* __restrict__ bih, const float* __restrict__ bhh,
    float* __restrict__ out, u32* __restrict__ hbuf, const u32* __restrict__ xpk) {
  const int wg = blockIdx.x, tid = threadIdx.x;
  const int m = wg >> 3, n = wg & 7;           // row-group, hcol-block
  const int lane = tid & 63, wave = tid >> 6;  // wave = gate index
  const int n16 = lane & 15, kgrp = lane >> 4;

  // ---- persistent B fragments: wave `g`, 2 N-tiles; col c=nt*16+n16 in block
  s16x8 BUh[2][8], BUl[2][8], BWh[2][8], BWl[2][8];
#pragma unroll
  for (int nt = 0; nt < 2; ++nt) {
    const int grow = wave * HID + n * HPB + nt * 16 + n16;
#pragma unroll
    for (int ks = 0; ks < 8; ++ks) {
      const int base = grow * DIM + ks * 32 + kgrp * 8;
#pragma unroll
      for (int e = 0; e < 8; ++e) {
        float uv = U[base + e];
        u16 uh = f2bf_rne(uv);
        BUh[nt][ks][e] = (short)uh;
        BUl[nt][ks][e] = (short)f2bf_rne(uv - bf2f(uh));
        float wv = W[base + e];
        u16 wh = f2bf_rne(wv);
        BWh[nt][ks][e] = (short)wh;
        BWl[nt][ks][e] = (short)f2bf_rne(wv - bf2f(wh));
      }
    }
  }

  // ---- cell mapping: 2 cells/thread (adjacent hcols)
  const int crow = tid >> 4;               // row within group
  const int cc   = (tid & 15) * 2;         // col-in-block (even)
  const int gb   = m * RPG + crow;         // global batch row
  const int ghc  = n * HPB + cc;           // global hcol (even)
  float bi[2], bf_[2], bg_[2], bo_[2];
#pragma unroll
  for (int e = 0; e < 2; ++e) {
    bi[e]  = bih[0 * HID + ghc + e] + bhh[0 * HID + ghc + e];
    bf_[e] = bih[1 * HID + ghc + e] + bhh[1 * HID + ghc + e];
    bg_[e] = bih[2 * HID + ghc + e] + bhh[2 * HID + ghc + e];
    bo_[e] = bih[3 * HID + ghc + e] + bhh[3 * HID + ghc + e];
  }
  const int len = lens[gb];
  float hreg[2] = {0.f, 0.f}, creg[2] = {0.f, 0.f};

  __shared__ u32 hstage[RPG * HID];        // 16KB swizzled packed h
  __shared__ float glds[4][RPG][HPB + 1];  // gate tiles (4 gates x 16 rows x 32)

  // ---- x fragment prefetch state (loaded at loop bottom for t+1)
  u32x4 xa[8][2];
  f32x4 xf[8][2];
  const long xrowbase = (long)(m * RPG + n16) * DIM + kgrp * 8;
  if constexpr (MODE == 0) {
#pragma unroll
    for (int ks = 0; ks < 8; ++ks) {
      xa[ks][0] = *(const u32x4*)(xpk + xrowbase + ks * 32);
      xa[ks][1] = *(const u32x4*)(xpk + xrowbase + ks * 32 + 4);
    }
  } else {
#pragma unroll
    for (int ks = 0; ks < 8; ++ks) {
      xf[ks][0] = *(const f32x4*)(x + xrowbase + ks * 32);
      xf[ks][1] = *(const f32x4*)(x + xrowbase + ks * 32 + 4);
    }
  }

  for (int t = 0; t < T_STEPS; ++t) {
    const int par = t & 1;

    // ---- poll+load h pairs (device-scope): tag==t in same 16B => fresh
    u32x4 P[8];
    {
      const u32* rb = hbuf + par * PLANE_U32 + m * REGION_U32 + crow * (HID * 2) + (tid & 15) * 32;
      for (;;) {
#pragma unroll
        for (int j = 0; j < 8; ++j)
          asm volatile("global_load_dwordx4 %0, %1, off sc0 sc1"
                       : "=v"(P[j]) : "v"(rb + j * 4) : "memory");
        asm volatile("s_waitcnt vmcnt(0)" ::: "memory");
        if (t == 0) break;
        bool stale = false;
#pragma unroll
        for (int j = 0; j < 8; ++j)
          stale |= (P[j][1] != (u32)t) || (P[j][3] != (u32)t);
        if (!__any(stale)) break;
      }
    }
    __builtin_amdgcn_sched_barrier(0);

    // ---- stage h (packed u32) to swizzled LDS
    {
      const int c0 = (tid & 15) * 16;
#pragma unroll
      for (int q = 0; q < 4; ++q) {
        const int byte = ((crow * HID + c0 + q * 4) * 4) ^ ((crow & 15) << 4);
        u32x4 v = {P[2 * q][0], P[2 * q][2], P[2 * q + 1][0], P[2 * q + 1][2]};
        *(u32x4*)((char*)hstage + byte) = v;
      }
    }
    __syncthreads();

    // ---- gate GEMM: 2 N-tiles, independent h/x accumulator chains
    f32x4 ah[2] = {{0.f, 0.f, 0.f, 0.f}, {0.f, 0.f, 0.f, 0.f}};
    f32x4 ax[2] = {{0.f, 0.f, 0.f, 0.f}, {0.f, 0.f, 0.f, 0.f}};
#pragma unroll
    for (int ks = 0; ks < 8; ++ks) {
      const int bb = (n16 * HID + kgrp * 8 + ks * 32) * 4;
      const int b0 = bb ^ ((n16 & 15) << 4);
      const int b1 = (bb + 16) ^ ((n16 & 15) << 4);
      u32x4 h0 = *(const u32x4*)((const char*)hstage + b0);
      u32x4 h1 = *(const u32x4*)((const char*)hstage + b1);
      s16x8 Hh, Hl, Xh, Xl;
      unpack8(h0, h1, Hh, Hl);
      if constexpr (MODE == 0) {
        unpack8(xa[ks][0], xa[ks][1], Xh, Xl);
      } else {
#pragma unroll
        for (int e = 0; e < 8; ++e) {
          float v = (e < 4 ? xf[ks][0][e] : xf[ks][1][e - 4]) * PKEEP;
          unsigned hb = __float_as_uint(v) & 0xFFFF0000u;
          Xh[e] = (short)(hb >> 16);
          Xl[e] = (short)(u16)(__float_as_uint(v - __uint_as_float(hb)) >> 16);
        }
      }
#pragma unroll
      for (int nt = 0; nt < 2; ++nt) {
        ah[nt] = __builtin_amdgcn_mfma_f32_16x16x32_bf16(Hh, BUh[nt][ks], ah[nt], 0, 0, 0);
        ax[nt] = __builtin_amdgcn_mfma_f32_16x16x32_bf16(Xh, BWh[nt][ks], ax[nt], 0, 0, 0);
        ah[nt] = __builtin_amdgcn_mfma_f32_16x16x32_bf16(Hl, BUh[nt][ks], ah[nt], 0, 0, 0);
        ax[nt] = __builtin_amdgcn_mfma_f32_16x16x32_bf16(Xl, BWh[nt][ks], ax[nt], 0, 0, 0);
        ah[nt] = __builtin_amdgcn_mfma_f32_16x16x32_bf16(Hh, BUl[nt][ks], ah[nt], 0, 0, 0);
        ax[nt] = __builtin_amdgcn_mfma_f32_16x16x32_bf16(Xh, BWl[nt][ks], ax[nt], 0, 0, 0);
      }
    }

    // ---- gate tiles -> LDS (D layout: col=lane&15, row=(lane>>4)*4+r)
#pragma unroll
    for (int nt = 0; nt < 2; ++nt)
#pragma unroll
      for (int r = 0; r < 4; ++r)
        glds[wave][kgrp * 4 + r][nt * 16 + n16] = ah[nt][r] + ax[nt][r];
    __syncthreads();

    // ---- cell update (2 cells/thread) + single 16B publish
    const bool act = (t < len);
    u32 pk[2];
    float hnew_s[2];
#pragma unroll
    for (int e = 0; e < 2; ++e) {
      float gi = glds[0][crow][cc + e] + bi[e];
      float gf = glds[1][crow][cc + e] + bf_[e];
      float gg = glds[2][crow][cc + e] + bg_[e];
      float go = glds[3][crow][cc + e] + bo_[e];
      float it = sigm(gi), ft = sigm(gf), ot = sigm(go);
      float gt = tanh_f(gg);
      float cnew = ft * creg[e] + it * gt;
      float hnew = ot * tanh_f(cnew);
      if (act) { creg[e] = cnew; hreg[e] = hnew; }
      hnew_s[e] = hnew;
      pk[e] = packbf(hreg[e] * PKEEP);
    }
    {
      u32x4 pv = {pk[0], (u32)(t + 1), pk[1], (u32)(t + 1)};
      dev_st_u32x4(hbuf + (par ^ 1) * PLANE_U32 + m * REGION_U32 + crow * (HID * 2) + ghc * 2, pv);
    }

    // ---- loop bottom: x prefetch for t+1 (hides under inter-step wait), out store
    if (t + 1 < T_STEPS) {
      const long xb = (long)(t + 1) * (BATCH * DIM) + xrowbase;
      if constexpr (MODE == 0) {
#pragma unroll
        for (int ks = 0; ks < 8; ++ks) {
          xa[ks][0] = *(const u32x4*)(xpk + xb + ks * 32);
          xa[ks][1] = *(const u32x4*)(xpk + xb + ks * 32 + 4);
        }
      } else {
#pragma unroll
        for (int ks = 0; ks < 8; ++ks) {
          xf[ks][0] = *(const f32x4*)(x + xb + ks * 32);
          xf[ks][1] = *(const f32x4*)(x + xb + ks * 32 + 4);
        }
      }
    }
#pragma unroll
    for (int e = 0; e < 2; ++e)
      out[(long)t * (BATCH * HID) + gb * HID + ghc + e] = act ? hnew_s[e] : 0.0f;
  }

  // ---- epilogue: h_n, c_n
#pragma unroll
  for (int e = 0; e < 2; ++e) {
    out[(long)T_STEPS * (BATCH * HID) + gb * HID + ghc + e] = hreg[e];
    out[(long)T_STEPS * (BATCH * HID) + BATCH * HID + gb * HID + ghc + e] = creg[e];
  }
}

#define RECUR_PARAMS                                                          \
  const float* __restrict__ x, const int* __restrict__ lens,                  \
  const float* __restrict__ W, const float* __restrict__ U,                   \
  const float* __restrict__ bih, const float* __restrict__ bhh,               \
  float* __restrict__ out, u32* __restrict__ hbuf, const u32* __restrict__ xpk
#define RECUR_ARGS x, lens, W, U, bih, bhh, out, hbuf, xpk

__global__ __launch_bounds__(256, 1) void lstm_recur_v6_xpk(RECUR_PARAMS) { recur_body<0>(RECUR_ARGS); }
__global__ __launch_bounds__(256, 1) void lstm_recur_v6_dir(RECUR_PARAMS) { recur_body<1>(RECUR_ARGS); }

extern "C" void kernel_launch(void* const* d_in, const int* in_sizes, int n_in,
                              void* d_out, int out_size, void* d_ws, size_t ws_size,
                              hipStream_t stream) {
  const float* x   = (const float*)d_in[0];
  const int*   len = (const int*)d_in[1];
  const float* W   = (const float*)d_in[2];
  const float* U   = (const float*)d_in[3];
  const float* bih = (const float*)d_in[4];
  const float* bhh = (const float*)d_in[5];
  float* out = (float*)d_out;
  char*  ws  = (char*)d_ws;
  u32* hbuf = (u32*)(ws + HBUF_OFF);
  char* big = ws + BIG_OFF;

  lstm_zero_ws<<<dim3((ZERO_INTS + 255) / 256), dim3(256), 0, stream>>>(hbuf);

  const size_t need_xp = (size_t)BIG_OFF + (size_t)XEL * 4;  // ~129MB
  if (ws_size >= need_xp) {
    u32* xpk = (u32*)big;
    lstm_xpack<<<dim3(32768), dim3(256), 0, stream>>>(x, xpk);
    lstm_recur_v6_xpk<<<dim3(32), dim3(256), 0, stream>>>(x, len, W, U, bih, bhh, out, hbuf, xpk);
  } else {
    lstm_recur_v6_dir<<<dim3(32), dim3(256), 0, stream>>>(x, len, W, U, bih, bhh, out, hbuf, nullptr);
  }
}

// Round 7
// 5697.646 us; speedup vs baseline: 2.1186x; 2.1186x over previous
//
#include <hip/hip_runtime.h>

// LSTM persistent recurrence v7 for MI355X.
// v5 protocol (64 WGs, device-scope tag-in-data dwordx2 publish) + three fixes:
//  1) single vmcnt(0) drain at loop BOTTOM (poll iterations wait only on own loads)
//  2) x staged via global_load_lds into double-buffered LDS (no VGPR liveness,
//     swizzled by pre-swizzled per-lane global source address)
//  3) conflict-free h staging: thread owns one 16B pair-line across 8 rows
//     (ds_write_b64 stride-8B, zero extra bank conflicts)

#define T_STEPS 2048
#define BATCH   64
#define DIM     256
#define HID     256
#define PKEEP   0.7f
#define NWG     64
#define RPG     16                       // rows per group
#define REGION_U32 (RPG * HID * 2)       // 8192 u32 (8B pairs per cell)
#define PLANE_U32  (4 * REGION_U32)      // 32768 u32 (128KB)
#define XEL     (T_STEPS * BATCH * DIM)  // 33554432

typedef __attribute__((ext_vector_type(8))) short s16x8;
typedef __attribute__((ext_vector_type(4))) float f32x4;
typedef __attribute__((ext_vector_type(4))) unsigned int u32x4;
typedef __attribute__((ext_vector_type(2))) unsigned int u32x2;
typedef unsigned int u32;
typedef unsigned short u16;

#define HBUF_OFF 4096
#define BIG_OFF  (1 << 20)
#define ZERO_INTS (2 * PLANE_U32)

#define HISEL 0x07060302u
#define LOSEL 0x05040100u

__device__ __forceinline__ u16 f2bf_rne(float f) {
  unsigned x = __float_as_uint(f);
  return (u16)((x + 0x7fffu + ((x >> 16) & 1u)) >> 16);
}
__device__ __forceinline__ float bf2f(u16 u) { return __uint_as_float(((unsigned)u) << 16); }
__device__ __forceinline__ float sigm(float v) { return 1.0f / (1.0f + __expf(-v)); }
__device__ __forceinline__ float tanh_f(float v) {
  float e = __expf(-2.0f * fabsf(v));
  float r = (1.0f - e) / (1.0f + e);
  return v < 0.0f ? -r : r;
}
__device__ __forceinline__ u32 packbf(float v) {
  u32 uh = __float_as_uint(v) & 0xFFFF0000u;
  u32 lo = (u32)f2bf_rne(v - __uint_as_float(uh));
  return uh | lo;
}
__device__ __forceinline__ void dev_st_u32x2(u32* p, u32x2 v) {
  asm volatile("global_store_dwordx2 %0, %1, off sc0 sc1" :: "v"(p), "v"(v) : "memory");
}
__device__ __forceinline__ void gload_lds16(const u32* g, u32* lds) {
  __builtin_amdgcn_global_load_lds(
      (const __attribute__((address_space(1))) u32*)g,
      (__attribute__((address_space(3))) u32*)lds, 16, 0, 0);
}
__device__ __forceinline__ void unpack8(u32x4 a, u32x4 b, s16x8& hi, s16x8& lo) {
  u32x4 H, L;
  H[0] = __builtin_amdgcn_perm(a[1], a[0], HISEL);
  H[1] = __builtin_amdgcn_perm(a[3], a[2], HISEL);
  H[2] = __builtin_amdgcn_perm(b[1], b[0], HISEL);
  H[3] = __builtin_amdgcn_perm(b[3], b[2], HISEL);
  L[0] = __builtin_amdgcn_perm(a[1], a[0], LOSEL);
  L[1] = __builtin_amdgcn_perm(a[3], a[2], LOSEL);
  L[2] = __builtin_amdgcn_perm(b[1], b[0], LOSEL);
  L[3] = __builtin_amdgcn_perm(b[3], b[2], LOSEL);
  hi = __builtin_bit_cast(s16x8, H);
  lo = __builtin_bit_cast(s16x8, L);
}

__global__ void lstm_zero_ws(u32* __restrict__ p) {
  int i = blockIdx.x * 256 + threadIdx.x;
  if (i < ZERO_INTS) p[i] = 0;
}

__global__ void lstm_xpack(const float* __restrict__ x, u32* __restrict__ xpk) {
  long i = ((long)blockIdx.x * 256 + threadIdx.x) * 4;
  if (i >= (long)XEL) return;
  f32x4 v = *(const f32x4*)(x + i);
  u32x4 o;
#pragma unroll
  for (int e = 0; e < 4; ++e) o[e] = packbf(v[e] * PKEEP);
  *(u32x4*)(xpk + i) = o;
}

// MODE: 0 = xpack planes (packed u32), 1 = direct fp32
template <int MODE>
__device__ __forceinline__ void recur_body(
    const float* __restrict__ x, const int* __restrict__ lens,
    const float* __restrict__ W, const float* __restrict__ U,
    const float* __restrict__ bih, const float* __restrict__ bhh,
    float* __restrict__ out, u32* __restrict__ hbuf, const u32* __restrict__ xpk) {
  const int wg = blockIdx.x, tid = threadIdx.x;
  const int m = wg >> 4, n = wg & 15;          // row-group, hcol-block
  const int lane = tid & 63, wave = tid >> 6;  // wave = gate index
  const int n16 = lane & 15, kgrp = lane >> 4;

  // ---- persistent B fragments (1 N-tile/wave): gate=wave, hcol=n*16+n16
  const int grow = wave * HID + n * 16 + n16;
  s16x8 BUh[8], BUl[8], BWh[8], BWl[8];
#pragma unroll
  for (int ks = 0; ks < 8; ++ks) {
    const int base = grow * DIM + ks * 32 + kgrp * 8;
#pragma unroll
    for (int e = 0; e < 8; ++e) {
      float uv = U[base + e];
      u16 uh = f2bf_rne(uv);
      BUh[ks][e] = (short)uh;
      BUl[ks][e] = (short)f2bf_rne(uv - bf2f(uh));
      float wv = W[base + e];
      u16 wh = f2bf_rne(wv);
      BWh[ks][e] = (short)wh;
      BWl[ks][e] = (short)f2bf_rne(wv - bf2f(wh));
    }
  }

  // ---- cell mapping (1 cell/thread)
  const int crow = tid >> 4, chc = tid & 15;
  const int gb = m * RPG + crow, ghc = n * 16 + chc;
  const float bi  = bih[0 * HID + ghc] + bhh[0 * HID + ghc];
  const float bfo = bih[1 * HID + ghc] + bhh[1 * HID + ghc];
  const float bg  = bih[2 * HID + ghc] + bhh[2 * HID + ghc];
  const float bo  = bih[3 * HID + ghc] + bhh[3 * HID + ghc];
  const int len = lens[gb];
  float hreg = 0.0f, creg = 0.0f;

  // ---- poll mapping: thread owns pair-column p across 8 rows (rh half)
  const int rh = tid >> 7, p = tid & 127;

  __shared__ u32 hstage[RPG * HID];        // 16KB swizzled packed h
  __shared__ u32 xstage[2][RPG * HID];     // 32KB double-buffered x (DMA)
  __shared__ float glds[4][RPG][17];       // gate tiles

  // ---- prologue: DMA x(t=0) into xstage[0] (pre-swizzled source)
  {
    const int R = wave * 4;
    const long tb = (long)(m * RPG) * DIM;
#pragma unroll
    for (int r = 0; r < 4; ++r) {
      const long src = tb + (long)(R + r) * DIM + 4 * (lane ^ ((R + r) & 15));
      if constexpr (MODE == 0) gload_lds16(xpk + src, &xstage[0][(R + r) * HID]);
      else                     gload_lds16((const u32*)x + src, &xstage[0][(R + r) * HID]);
    }
  }

  for (int t = 0; t < T_STEPS; ++t) {
    const int par = t & 1, cur = t & 1;

    // ---- poll h pair-lines (device-scope); waits only on own 8 loads
    u32x4 P[8];
    {
      const u32* rb = hbuf + par * PLANE_U32 + m * REGION_U32 + rh * (8 * 512) + p * 4;
      for (;;) {
#pragma unroll
        for (int j = 0; j < 8; ++j)
          asm volatile("global_load_dwordx4 %0, %1, off sc0 sc1"
                       : "=v"(P[j]) : "v"(rb + j * 512) : "memory");
        asm volatile("s_waitcnt vmcnt(0)" ::: "memory");
        if (t == 0) break;
        bool stale = false;
#pragma unroll
        for (int j = 0; j < 8; ++j)
          stale |= (P[j][1] != (u32)t) || (P[j][3] != (u32)t);
        if (!__any(stale)) break;
      }
    }
    __builtin_amdgcn_sched_barrier(0);

    // ---- stage h: ds_write_b64, conflict-free (8B lane stride within row)
#pragma unroll
    for (int j = 0; j < 8; ++j) {
      const int row = rh * 8 + j;
      const int byte = (row * 1024 + p * 8) ^ (row << 4);
      u32x2 v = {P[j][0], P[j][2]};
      *(u32x2*)((char*)hstage + byte) = v;
    }
    __syncthreads();

    // ---- gate GEMM: h and x chains (48 MFMAs/wave)
    const int swz = n16 << 4;
    f32x4 ah = {0.f, 0.f, 0.f, 0.f}, ax = {0.f, 0.f, 0.f, 0.f};
#pragma unroll
    for (int ks = 0; ks < 8; ++ks) {
      const int bb = n16 * 1024 + (kgrp * 8 + ks * 32) * 4;
      u32x4 h0 = *(const u32x4*)((const char*)hstage + (bb ^ swz));
      u32x4 h1 = *(const u32x4*)((const char*)hstage + ((bb + 16) ^ swz));
      s16x8 Hh, Hl, Xh, Xl;
      unpack8(h0, h1, Hh, Hl);
      if constexpr (MODE == 0) {
        u32x4 x0 = *(const u32x4*)((const char*)xstage[cur] + (bb ^ swz));
        u32x4 x1 = *(const u32x4*)((const char*)xstage[cur] + ((bb + 16) ^ swz));
        unpack8(x0, x1, Xh, Xl);
      } else {
        f32x4 f0 = *(const f32x4*)((const char*)xstage[cur] + (bb ^ swz));
        f32x4 f1 = *(const f32x4*)((const char*)xstage[cur] + ((bb + 16) ^ swz));
#pragma unroll
        for (int e = 0; e < 8; ++e) {
          float v = (e < 4 ? f0[e] : f1[e - 4]) * PKEEP;
          unsigned hb = __float_as_uint(v) & 0xFFFF0000u;
          Xh[e] = (short)(hb >> 16);
          Xl[e] = (short)(u16)(__float_as_uint(v - __uint_as_float(hb)) >> 16);
        }
      }
      ah = __builtin_amdgcn_mfma_f32_16x16x32_bf16(Hh, BUh[ks], ah, 0, 0, 0);
      ax = __builtin_amdgcn_mfma_f32_16x16x32_bf16(Xh, BWh[ks], ax, 0, 0, 0);
      ah = __builtin_amdgcn_mfma_f32_16x16x32_bf16(Hl, BUh[ks], ah, 0, 0, 0);
      ax = __builtin_amdgcn_mfma_f32_16x16x32_bf16(Xl, BWh[ks], ax, 0, 0, 0);
      ah = __builtin_amdgcn_mfma_f32_16x16x32_bf16(Hh, BUl[ks], ah, 0, 0, 0);
      ax = __builtin_amdgcn_mfma_f32_16x16x32_bf16(Xh, BWl[ks], ax, 0, 0, 0);
    }

    // ---- gate tile -> LDS (D layout: col=lane&15, row=(lane>>4)*4+r)
#pragma unroll
    for (int r = 0; r < 4; ++r) glds[wave][kgrp * 4 + r][n16] = ah[r] + ax[r];
    __syncthreads();

    // ---- cell update + publish {packed, tag} (8B device-scope store)
    float gi = glds[0][crow][chc] + bi;
    float gf = glds[1][crow][chc] + bfo;
    float gg = glds[2][crow][chc] + bg;
    float go = glds[3][crow][chc] + bo;
    float it = sigm(gi), ft = sigm(gf), ot = sigm(go);
    float gt = tanh_f(gg);
    float cnew = ft * creg + it * gt;
    float hnew = ot * tanh_f(cnew);
    const bool act = (t < len);
    if (act) { creg = cnew; hreg = hnew; }
    {
      u32x2 pv = {packbf(hreg * PKEEP), (u32)(t + 1)};
      dev_st_u32x2(hbuf + (par ^ 1) * PLANE_U32 + m * REGION_U32 + crow * 512 + ghc * 2, pv);
    }

    // ---- out store + x DMA for t+1 (hides under publish window)
    out[(long)t * (BATCH * HID) + gb * HID + ghc] = act ? hnew : 0.0f;
    if (t + 1 < T_STEPS) {
      const int R = wave * 4;
      const long tb = (long)(t + 1) * (BATCH * DIM) + (long)(m * RPG) * DIM;
#pragma unroll
      for (int r = 0; r < 4; ++r) {
        const long src = tb + (long)(R + r) * DIM + 4 * (lane ^ ((R + r) & 15));
        if constexpr (MODE == 0) gload_lds16(xpk + src, &xstage[cur ^ 1][(R + r) * HID]);
        else                     gload_lds16((const u32*)x + src, &xstage[cur ^ 1][(R + r) * HID]);
      }
    }

    // ---- single drain point: publish + out + DMA all complete here,
    //      overlapped with the other WGs' cell/publish phase
    asm volatile("s_waitcnt vmcnt(0)" ::: "memory");
    __builtin_amdgcn_sched_barrier(0);
  }

  // ---- epilogue: h_n, c_n
  out[(long)T_STEPS * (BATCH * HID) + gb * HID + ghc] = hreg;
  out[(long)T_STEPS * (BATCH * HID) + BATCH * HID + gb * HID + ghc] = creg;
}

#define RECUR_PARAMS                                                          \
  const float* __restrict__ x, const int* __restrict__ lens,                  \
  const float* __restrict__ W, const float* __restrict__ U,                   \
  const float* __restrict__ bih, const float* __restrict__ bhh,               \
  float* __restrict__ out, u32* __restrict__ hbuf, const u32* __restrict__ xpk
#define RECUR_ARGS x, lens, W, U, bih, bhh, out, hbuf, xpk

__global__ __launch_bounds__(256, 1) void lstm_recur_v7_xpk(RECUR_PARAMS) { recur_body<0>(RECUR_ARGS); }
__global__ __launch_bounds__(256, 1) void lstm_recur_v7_dir(RECUR_PARAMS) { recur_body<1>(RECUR_ARGS); }

extern "C" void kernel_launch(void* const* d_in, const int* in_sizes, int n_in,
                              void* d_out, int out_size, void* d_ws, size_t ws_size,
                              hipStream_t stream) {
  const float* x   = (const float*)d_in[0];
  const int*   len = (const int*)d_in[1];
  const float* W   = (const float*)d_in[2];
  const float* U   = (const float*)d_in[3];
  const float* bih = (const float*)d_in[4];
  const float* bhh = (const float*)d_in[5];
  float* out = (float*)d_out;
  char*  ws  = (char*)d_ws;
  u32* hbuf = (u32*)(ws + HBUF_OFF);
  char* big = ws + BIG_OFF;

  lstm_zero_ws<<<dim3((ZERO_INTS + 255) / 256), dim3(256), 0, stream>>>(hbuf);

  const size_t need_xp = (size_t)BIG_OFF + (size_t)XEL * 4;  // ~129MB
  if (ws_size >= need_xp) {
    u32* xpk = (u32*)big;
    lstm_xpack<<<dim3(32768), dim3(256), 0, stream>>>(x, xpk);
    lstm_recur_v7_xpk<<<dim3(NWG), dim3(256), 0, stream>>>(x, len, W, U, bih, bhh, out, hbuf, xpk);
  } else {
    lstm_recur_v7_dir<<<dim3(NWG), dim3(256), 0, stream>>>(x, len, W, U, bih, bhh, out, hbuf, nullptr);
  }
}

// Round 8
// 5194.960 us; speedup vs baseline: 2.3236x; 1.0968x over previous
//
#include <hip/hip_runtime.h>

// LSTM persistent recurrence v8 for MI355X.
// v7 + gate-interleaved N-tiles: each wave owns 4 hcols x all 4 gates
// (col = gate*4 + hc). Cell gates gathered by an in-wave 4x4 reg<->lane
// butterfly transpose (ds_swizzle xor4/xor8) -- no gate LDS, no second
// barrier; each lane publishes its cell immediately after its wave's MFMA.

#define T_STEPS 2048
#define BATCH   64
#define DIM     256
#define HID     256
#define PKEEP   0.7f
#define NWG     64
#define RPG     16                       // rows per group
#define REGION_U32 (RPG * HID * 2)       // 8192 u32 (8B pair per cell)
#define PLANE_U32  (4 * REGION_U32)      // 32768 u32 (128KB)
#define XEL     (T_STEPS * BATCH * DIM)  // 33554432

typedef __attribute__((ext_vector_type(8))) short s16x8;
typedef __attribute__((ext_vector_type(4))) float f32x4;
typedef __attribute__((ext_vector_type(4))) unsigned int u32x4;
typedef __attribute__((ext_vector_type(2))) unsigned int u32x2;
typedef unsigned int u32;
typedef unsigned short u16;

#define HBUF_OFF 4096
#define BIG_OFF  (1 << 20)
#define ZERO_INTS (2 * PLANE_U32)

#define HISEL 0x07060302u
#define LOSEL 0x05040100u

__device__ __forceinline__ u16 f2bf_rne(float f) {
  unsigned x = __float_as_uint(f);
  return (u16)((x + 0x7fffu + ((x >> 16) & 1u)) >> 16);
}
__device__ __forceinline__ float bf2f(u16 u) { return __uint_as_float(((unsigned)u) << 16); }
__device__ __forceinline__ float sigm(float v) { return 1.0f / (1.0f + __expf(-v)); }
__device__ __forceinline__ float tanh_f(float v) {
  float e = __expf(-2.0f * fabsf(v));
  float r = (1.0f - e) / (1.0f + e);
  return v < 0.0f ? -r : r;
}
__device__ __forceinline__ u32 packbf(float v) {
  u32 uh = __float_as_uint(v) & 0xFFFF0000u;
  u32 lo = (u32)f2bf_rne(v - __uint_as_float(uh));
  return uh | lo;
}
__device__ __forceinline__ void dev_st_u32x2(u32* p, u32x2 v) {
  asm volatile("global_store_dwordx2 %0, %1, off sc0 sc1" :: "v"(p), "v"(v) : "memory");
}
__device__ __forceinline__ void gload_lds16(const u32* g, u32* lds) {
  __builtin_amdgcn_global_load_lds(
      (const __attribute__((address_space(1))) u32*)g,
      (__attribute__((address_space(3))) u32*)lds, 16, 0, 0);
}
__device__ __forceinline__ void unpack8(u32x4 a, u32x4 b, s16x8& hi, s16x8& lo) {
  u32x4 H, L;
  H[0] = __builtin_amdgcn_perm(a[1], a[0], HISEL);
  H[1] = __builtin_amdgcn_perm(a[3], a[2], HISEL);
  H[2] = __builtin_amdgcn_perm(b[1], b[0], HISEL);
  H[3] = __builtin_amdgcn_perm(b[3], b[2], HISEL);
  L[0] = __builtin_amdgcn_perm(a[1], a[0], LOSEL);
  L[1] = __builtin_amdgcn_perm(a[3], a[2], LOSEL);
  L[2] = __builtin_amdgcn_perm(b[1], b[0], LOSEL);
  L[3] = __builtin_amdgcn_perm(b[3], b[2], LOSEL);
  hi = __builtin_bit_cast(s16x8, H);
  lo = __builtin_bit_cast(s16x8, L);
}

// 4x4 transpose between reg index (2 bits) and lane bits 2-3.
// In : reg q = gate(lane bits 2-3) value at row kgrp*4+q.
// Out: reg r = gate r value at row kgrp*4+(lane bits 2-3).
__device__ __forceinline__ void xpose4(f32x4& a, bool b2, bool b3) {
  {  // swap reg bit0 <-> lane bit2 (xor 4 => offset 0x101F)
    int t0 = __builtin_amdgcn_ds_swizzle(__float_as_int(a[1]), 0x101F);
    int u0 = __builtin_amdgcn_ds_swizzle(__float_as_int(a[0]), 0x101F);
    int t1 = __builtin_amdgcn_ds_swizzle(__float_as_int(a[3]), 0x101F);
    int u1 = __builtin_amdgcn_ds_swizzle(__float_as_int(a[2]), 0x101F);
    float A0 = b2 ? __int_as_float(t0) : a[0];
    float A1 = b2 ? a[1] : __int_as_float(u0);
    float A2 = b2 ? __int_as_float(t1) : a[2];
    float A3 = b2 ? a[3] : __int_as_float(u1);
    a[0] = A0; a[1] = A1; a[2] = A2; a[3] = A3;
  }
  {  // swap reg bit1 <-> lane bit3 (xor 8 => offset 0x201F)
    int t0 = __builtin_amdgcn_ds_swizzle(__float_as_int(a[2]), 0x201F);
    int u0 = __builtin_amdgcn_ds_swizzle(__float_as_int(a[0]), 0x201F);
    int t1 = __builtin_amdgcn_ds_swizzle(__float_as_int(a[3]), 0x201F);
    int u1 = __builtin_amdgcn_ds_swizzle(__float_as_int(a[1]), 0x201F);
    float A0 = b3 ? __int_as_float(t0) : a[0];
    float A2 = b3 ? a[2] : __int_as_float(u0);
    float A1 = b3 ? __int_as_float(t1) : a[1];
    float A3 = b3 ? a[3] : __int_as_float(u1);
    a[0] = A0; a[1] = A1; a[2] = A2; a[3] = A3;
  }
}

__global__ void lstm_zero_ws(u32* __restrict__ p) {
  int i = blockIdx.x * 256 + threadIdx.x;
  if (i < ZERO_INTS) p[i] = 0;
}

__global__ void lstm_xpack(const float* __restrict__ x, u32* __restrict__ xpk) {
  long i = ((long)blockIdx.x * 256 + threadIdx.x) * 4;
  if (i >= (long)XEL) return;
  f32x4 v = *(const f32x4*)(x + i);
  u32x4 o;
#pragma unroll
  for (int e = 0; e < 4; ++e) o[e] = packbf(v[e] * PKEEP);
  *(u32x4*)(xpk + i) = o;
}

// MODE: 0 = xpack planes (packed u32), 1 = direct fp32
template <int MODE>
__device__ __forceinline__ void recur_body(
    const float* __restrict__ x, const int* __restrict__ lens,
    const float* __restrict__ W, const float* __restrict__ U,
    const float* __restrict__ bih, const float* __restrict__ bhh,
    float* __restrict__ out, u32* __restrict__ hbuf, const u32* __restrict__ xpk) {
  const int wg = blockIdx.x, tid = threadIdx.x;
  const int m = wg >> 4, n = wg & 15;          // row-group, hcol-block
  const int lane = tid & 63, wave = tid >> 6;
  const int n16 = lane & 15, kgrp = lane >> 4;

  // ---- persistent B fragments, gate-interleaved: col n16 -> gate (n16>>2),
  //      hcol n*16 + wave*4 + (n16&3)
  const int ghc_w = n * 16 + wave * 4 + (n16 & 3);
  const int grow = (n16 >> 2) * HID + ghc_w;
  s16x8 BUh[8], BUl[8], BWh[8], BWl[8];
#pragma unroll
  for (int ks = 0; ks < 8; ++ks) {
    const int base = grow * DIM + ks * 32 + kgrp * 8;
#pragma unroll
    for (int e = 0; e < 8; ++e) {
      float uv = U[base + e];
      u16 uh = f2bf_rne(uv);
      BUh[ks][e] = (short)uh;
      BUl[ks][e] = (short)f2bf_rne(uv - bf2f(uh));
      float wv = W[base + e];
      u16 wh = f2bf_rne(wv);
      BWh[ks][e] = (short)wh;
      BWl[ks][e] = (short)f2bf_rne(wv - bf2f(wh));
    }
  }

  // ---- cell ownership (post-transpose): lane owns (row_l, ghc_w)
  const bool b2 = (lane >> 2) & 1, b3 = (lane >> 3) & 1;
  const int row_l = kgrp * 4 + (n16 >> 2);
  const int gb = m * RPG + row_l;
  const float bi  = bih[0 * HID + ghc_w] + bhh[0 * HID + ghc_w];
  const float bfo = bih[1 * HID + ghc_w] + bhh[1 * HID + ghc_w];
  const float bg  = bih[2 * HID + ghc_w] + bhh[2 * HID + ghc_w];
  const float bo  = bih[3 * HID + ghc_w] + bhh[3 * HID + ghc_w];
  const int len = lens[gb];
  float hreg = 0.0f, creg = 0.0f;

  // ---- poll mapping: thread owns pair-column p across 8 rows (rh half)
  const int rh = tid >> 7, p = tid & 127;

  __shared__ u32 hstage[2][RPG * HID];     // 32KB parity-double-buffered h
  __shared__ u32 xstage[2][RPG * HID];     // 32KB double-buffered x (DMA)

  // ---- prologue: DMA x(t=0) into xstage[0] (pre-swizzled source)
  {
    const int R = wave * 4;
    const long tb = (long)(m * RPG) * DIM;
#pragma unroll
    for (int r = 0; r < 4; ++r) {
      const long src = tb + (long)(R + r) * DIM + 4 * (lane ^ ((R + r) & 15));
      if constexpr (MODE == 0) gload_lds16(xpk + src, &xstage[0][(R + r) * HID]);
      else                     gload_lds16((const u32*)x + src, &xstage[0][(R + r) * HID]);
    }
  }

  for (int t = 0; t < T_STEPS; ++t) {
    const int par = t & 1;

    // ---- poll h pair-lines (device-scope); waits only on own 8 loads
    u32x4 P[8];
    {
      const u32* rb = hbuf + par * PLANE_U32 + m * REGION_U32 + rh * (8 * 512) + p * 4;
      for (;;) {
#pragma unroll
        for (int j = 0; j < 8; ++j)
          asm volatile("global_load_dwordx4 %0, %1, off sc0 sc1"
                       : "=v"(P[j]) : "v"(rb + j * 512) : "memory");
        asm volatile("s_waitcnt vmcnt(0)" ::: "memory");
        if (t == 0) break;
        bool stale = false;
#pragma unroll
        for (int j = 0; j < 8; ++j)
          stale |= (P[j][1] != (u32)t) || (P[j][3] != (u32)t);
        if (!__any(stale)) break;
      }
    }
    __builtin_amdgcn_sched_barrier(0);

    // ---- stage h into hstage[par]: ds_write_b64, conflict-free
#pragma unroll
    for (int j = 0; j < 8; ++j) {
      const int row = rh * 8 + j;
      const int byte = (row * 1024 + p * 8) ^ (row << 4);
      u32x2 v = {P[j][0], P[j][2]};
      *(u32x2*)((char*)hstage[par] + byte) = v;
    }
    __syncthreads();  // the ONLY barrier per step

    // ---- gate GEMM: h and x chains (48 MFMAs/wave)
    const int swz = n16 << 4;
    f32x4 ah = {0.f, 0.f, 0.f, 0.f}, ax = {0.f, 0.f, 0.f, 0.f};
#pragma unroll
    for (int ks = 0; ks < 8; ++ks) {
      const int bb = n16 * 1024 + (kgrp * 8 + ks * 32) * 4;
      u32x4 h0 = *(const u32x4*)((const char*)hstage[par] + (bb ^ swz));
      u32x4 h1 = *(const u32x4*)((const char*)hstage[par] + ((bb + 16) ^ swz));
      s16x8 Hh, Hl, Xh, Xl;
      unpack8(h0, h1, Hh, Hl);
      if constexpr (MODE == 0) {
        u32x4 x0 = *(const u32x4*)((const char*)xstage[par] + (bb ^ swz));
        u32x4 x1 = *(const u32x4*)((const char*)xstage[par] + ((bb + 16) ^ swz));
        unpack8(x0, x1, Xh, Xl);
      } else {
        f32x4 f0 = *(const f32x4*)((const char*)xstage[par] + (bb ^ swz));
        f32x4 f1 = *(const f32x4*)((const char*)xstage[par] + ((bb + 16) ^ swz));
#pragma unroll
        for (int e = 0; e < 8; ++e) {
          float v = (e < 4 ? f0[e] : f1[e - 4]) * PKEEP;
          unsigned hb = __float_as_uint(v) & 0xFFFF0000u;
          Xh[e] = (short)(hb >> 16);
          Xl[e] = (short)(u16)(__float_as_uint(v - __uint_as_float(hb)) >> 16);
        }
      }
      ah = __builtin_amdgcn_mfma_f32_16x16x32_bf16(Hh, BUh[ks], ah, 0, 0, 0);
      ax = __builtin_amdgcn_mfma_f32_16x16x32_bf16(Xh, BWh[ks], ax, 0, 0, 0);
      ah = __builtin_amdgcn_mfma_f32_16x16x32_bf16(Hl, BUh[ks], ah, 0, 0, 0);
      ax = __builtin_amdgcn_mfma_f32_16x16x32_bf16(Xl, BWh[ks], ax, 0, 0, 0);
      ah = __builtin_amdgcn_mfma_f32_16x16x32_bf16(Hh, BUl[ks], ah, 0, 0, 0);
      ax = __builtin_amdgcn_mfma_f32_16x16x32_bf16(Xh, BWl[ks], ax, 0, 0, 0);
    }

    // ---- in-wave gather: reg<->lane-bit transpose; lane now holds i,f,g,o
    f32x4 g4 = ah + ax;
    xpose4(g4, b2, b3);

    // ---- cell update + immediate per-lane publish (no barrier!)
    float gi = g4[0] + bi, gf = g4[1] + bfo, gg = g4[2] + bg, go = g4[3] + bo;
    float it = sigm(gi), ft = sigm(gf), ot = sigm(go);
    float gt = tanh_f(gg);
    float cnew = ft * creg + it * gt;
    float hnew = ot * tanh_f(cnew);
    const bool act = (t < len);
    if (act) { creg = cnew; hreg = hnew; }
    {
      u32x2 pv = {packbf(hreg * PKEEP), (u32)(t + 1)};
      dev_st_u32x2(hbuf + (par ^ 1) * PLANE_U32 + m * REGION_U32 + row_l * 512 + ghc_w * 2, pv);
    }

    // ---- x DMA for t+1 + out store (latency hidden behind next-step wait)
    if (t + 1 < T_STEPS) {
      const int R = wave * 4;
      const long tb = (long)(t + 1) * (BATCH * DIM) + (long)(m * RPG) * DIM;
#pragma unroll
      for (int r = 0; r < 4; ++r) {
        const long src = tb + (long)(R + r) * DIM + 4 * (lane ^ ((R + r) & 15));
        if constexpr (MODE == 0) gload_lds16(xpk + src, &xstage[par ^ 1][(R + r) * HID]);
        else                     gload_lds16((const u32*)x + src, &xstage[par ^ 1][(R + r) * HID]);
      }
    }
    out[(long)t * (BATCH * HID) + gb * HID + ghc_w] = act ? hnew : 0.0f;

    // ---- single drain: publish + DMA + out all complete here
    asm volatile("s_waitcnt vmcnt(0)" ::: "memory");
    __builtin_amdgcn_sched_barrier(0);
  }

  // ---- epilogue: h_n, c_n
  out[(long)T_STEPS * (BATCH * HID) + gb * HID + ghc_w] = hreg;
  out[(long)T_STEPS * (BATCH * HID) + BATCH * HID + gb * HID + ghc_w] = creg;
}

#define RECUR_PARAMS                                                          \
  const float* __restrict__ x, const int* __restrict__ lens,                  \
  const float* __restrict__ W, const float* __restrict__ U,                   \
  const float* __restrict__ bih, const float* __restrict__ bhh,               \
  float* __restrict__ out, u32* __restrict__ hbuf, const u32* __restrict__ xpk
#define RECUR_ARGS x, lens, W, U, bih, bhh, out, hbuf, xpk

__global__ __launch_bounds__(256, 1) void lstm_recur_v8_xpk(RECUR_PARAMS) { recur_body<0>(RECUR_ARGS); }
__global__ __launch_bounds__(256, 1) void lstm_recur_v8_dir(RECUR_PARAMS) { recur_body<1>(RECUR_ARGS); }

extern "C" void kernel_launch(void* const* d_in, const int* in_sizes, int n_in,
                              void* d_out, int out_size, void* d_ws, size_t ws_size,
                              hipStream_t stream) {
  const float* x   = (const float*)d_in[0];
  const int*   len = (const int*)d_in[1];
  const float* W   = (const float*)d_in[2];
  const float* U   = (const float*)d_in[3];
  const float* bih = (const float*)d_in[4];
  const float* bhh = (const float*)d_in[5];
  float* out = (float*)d_out;
  char*  ws  = (char*)d_ws;
  u32* hbuf = (u32*)(ws + HBUF_OFF);
  char* big = ws + BIG_OFF;

  lstm_zero_ws<<<dim3((ZERO_INTS + 255) / 256), dim3(256), 0, stream>>>(hbuf);

  const size_t need_xp = (size_t)BIG_OFF + (size_t)XEL * 4;  // ~129MB
  if (ws_size >= need_xp) {
    u32* xpk = (u32*)big;
    lstm_xpack<<<dim3(32768), dim3(256), 0, stream>>>(x, xpk);
    lstm_recur_v8_xpk<<<dim3(NWG), dim3(256), 0, stream>>>(x, len, W, U, bih, bhh, out, hbuf, xpk);
  } else {
    lstm_recur_v8_dir<<<dim3(NWG), dim3(256), 0, stream>>>(x, len, W, U, bih, bhh, out, hbuf, nullptr);
  }
}